// Round 4
// baseline (327.926 us; speedup 1.0000x reference)
//
#include <hip/hip_runtime.h>
#include <stdint.h>

#define M_TOT 8192
#define N_TOT 4096
#define K_TOT 4096
#define NTILE 64   // K-tiles of BK=64

typedef __attribute__((ext_vector_type(8))) short bf16x8;
typedef __attribute__((ext_vector_type(16))) float f32x16;
typedef __attribute__((ext_vector_type(2))) unsigned short u16x2;
typedef __attribute__((ext_vector_type(4))) unsigned short u16x4;

typedef const __attribute__((address_space(1))) void* gas1;
typedef __attribute__((address_space(3))) void* las3;

__device__ __forceinline__ unsigned short bf16_rne(float f) {
    union { float f; unsigned int u; } v; v.f = f;
    unsigned int u = v.u;
    return (unsigned short)((u + 0x7FFFu + ((u >> 16) & 1u)) >> 16);
}

// Exact collapse of the reference FP4(E2M1) quant-dequant on a = |w|/scale.
__device__ __forceinline__ float fp4_qdq(float wv, float scale) {
    float a = fabsf(wv) / scale;
    float q;
    if      (a <= 0.25f) q = 0.0f;
    else if (a <  1.0f ) q = 0.5f;
    else if (a <= 1.25f) q = 1.0f;
    else if (a <  2.0f ) q = 1.5f;
    else if (a <= 2.5f ) q = 2.0f;
    else if (a <  4.0f ) q = 3.0f;
    else if (a <= 5.0f ) q = 4.0f;
    else                 q = 6.0f;
    float d = q * scale;
    return wv < 0.0f ? -d : d;
}

__global__ __launch_bounds__(256) void quant_w_kernel(const float* __restrict__ w,
                                                      unsigned short* __restrict__ wb) {
    int gwave = blockIdx.x * 4 + (threadIdx.x >> 6);
    int lane = threadIdx.x & 63;
    size_t base = (size_t)gwave * 128;
    float2 v = ((const float2*)(w + base))[lane];
    float mx = fmaxf(fabsf(v.x), fabsf(v.y));
    #pragma unroll
    for (int off = 32; off; off >>= 1) mx = fmaxf(mx, __shfl_xor(mx, off));
    float scale = fmaxf(mx / 6.0f, 1e-8f);
    u16x2 o;
    o.x = bf16_rne(fp4_qdq(v.x, scale));
    o.y = bf16_rne(fp4_qdq(v.y, scale));
    *(u16x2*)(wb + base + (size_t)lane * 2) = o;
}

__global__ __launch_bounds__(256) void cvt_x_kernel(const float* __restrict__ x,
                                                    unsigned short* __restrict__ xb) {
    const int total4 = (M_TOT * K_TOT) / 4;
    int stride = gridDim.x * blockDim.x;
    for (int i = blockIdx.x * blockDim.x + threadIdx.x; i < total4; i += stride) {
        float4 v = ((const float4*)x)[i];
        u16x4 o;
        o.x = bf16_rne(v.x); o.y = bf16_rne(v.y);
        o.z = bf16_rne(v.z); o.w = bf16_rne(v.w);
        ((u16x4*)xb)[i] = o;
    }
}

// ---------------- 256x256 8-phase GEMM, 32x32x16 MFMA ----------------
// C[m][n] = sum_k A[m][k]*B[n][k] + bias[n]; A,B bf16 K-contig, C f32.
// 512 threads = 8 waves (2M x 4N); per-wave output 128x64 = 4x2 tiles of 32x32.
// LDS: 2 buffers x { A_k0, A_k1, B_k0, B_k1 } of [256 rows][32 cols] bf16 (16KB each).
// Rotation swizzle within 64B rows: LDS pos p holds source granule (p-(r>>1))&3.
// Single counted vmcnt(6) per K-tile (end of phase 4); never 0 in the loop.

#define BAR()      __builtin_amdgcn_s_barrier()
#define SCHEDB()   __builtin_amdgcn_sched_barrier(0)
#define WAITLGKM() asm volatile("s_waitcnt lgkmcnt(0)" ::: "memory")
#define WAITVM6()  asm volatile("s_waitcnt vmcnt(6)" ::: "memory")
#define WAITVM0()  asm volatile("s_waitcnt vmcnt(0)" ::: "memory")

__global__ __launch_bounds__(512) void gemm_kernel(const unsigned short* __restrict__ A,
                                                   const unsigned short* __restrict__ B,
                                                   const float* __restrict__ bias,
                                                   float* __restrict__ C) {
    extern __shared__ unsigned char lds[];   // 131072 bytes

    // 2D-chunked XCD swizzle: XCD = bid&7 owns a 16tm x 4tn rectangle;
    // its 32 concurrently-resident blocks cover 8tm x 4tn -> L2 working set ~384KB.
    const int bid = blockIdx.x;
    const int xcd = bid & 7;
    const int idx = bid >> 3;          // 0..63
    const int tm = ((xcd >> 2) << 4) + (idx >> 2);   // 0..31
    const int tn = ((xcd & 3) << 2) + (idx & 3);     // 0..15
    const int m0 = tm << 8, n0 = tn << 8;

    const int t = threadIdx.x;
    const int l = t & 63;
    const int wid = t >> 6;
    const int wr = wid >> 2;   // 0..1
    const int wc = wid & 3;    // 0..3
    const int l31 = l & 31;
    const int h32 = l >> 5;    // k-half selector for 32x32 fragments

    // Staging: thread t covers granules G0=t, G1=512+t of each 1024-granule region.
    // Row r=G>>2, LDS pos p=G&3 holds source granule s=(p-(r>>1))&3.
    const int r0g = t >> 2,        p0g = t & 3;
    const int r1g = (512 + t) >> 2, p1g = t & 3;
    const int s0g = (p0g - (r0g >> 1)) & 3;
    const int s1g = (p1g - (r1g >> 1)) & 3;
    const unsigned short* arow0 = A + (size_t)(m0 + r0g) * K_TOT + s0g * 8;
    const unsigned short* arow1 = A + (size_t)(m0 + r1g) * K_TOT + s1g * 8;
    const unsigned short* brow0 = B + (size_t)(n0 + r0g) * K_TOT + s0g * 8;
    const unsigned short* brow1 = B + (size_t)(n0 + r1g) * K_TOT + s1g * 8;
    const unsigned lo0 = (unsigned)t * 16u;
    const unsigned lo1 = lo0 + 8192u;

#define STAGE(ROW0, ROW1, MATOFF, KK, TT, BB) do {                                   \
      const unsigned _base = (unsigned)(BB) * 65536u + (MATOFF) + (KK) * 16384u;     \
      const int _ko = (TT) * 64 + (KK) * 32;                                         \
      __builtin_amdgcn_global_load_lds((gas1)(ROW0 + _ko), (las3)(lds + _base + lo0), 16, 0, 0); \
      __builtin_amdgcn_global_load_lds((gas1)(ROW1 + _ko), (las3)(lds + _base + lo1), 16, 0, 0); \
    } while (0)
#define STAGE_A(KK, TT, BB) STAGE(arow0, arow1, 0u, KK, TT, BB)
#define STAGE_B(KK, TT, BB) STAGE(brow0, brow1, 32768u, KK, TT, BB)

// 32x32x16 A-frag: row = l&31, k-elems (l>>5)*8..+8 within the ks-th 16-K slice.
// Logical granule q = ks*2 + (l>>5); swizzled pos p = (q + (row>>1)) & 3.
#define LOAD_A32(MIH, KK, BB) do {                                                   \
      _Pragma("unroll")                                                              \
      for (int mi2 = 0; mi2 < 2; ++mi2)                                              \
        _Pragma("unroll")                                                            \
        for (int ks = 0; ks < 2; ++ks) {                                             \
          int ra = wr * 128 + ((MIH) * 2 + mi2) * 32 + l31;                          \
          unsigned pa = (unsigned)((ks * 2 + h32 + (ra >> 1)) & 3);                  \
          af[mi2][ks] = *(const bf16x8*)(lds + (unsigned)(BB) * 65536u               \
                            + (KK) * 16384u + (unsigned)ra * 64u + pa * 16u);        \
        } } while (0)

#define LOAD_B32(KK, BB) do {                                                        \
      _Pragma("unroll")                                                              \
      for (int nj = 0; nj < 2; ++nj)                                                 \
        _Pragma("unroll")                                                            \
        for (int ks = 0; ks < 2; ++ks) {                                             \
          int rb = wc * 64 + nj * 32 + l31;                                          \
          unsigned pb = (unsigned)((ks * 2 + h32 + (rb >> 1)) & 3);                  \
          bg[nj][ks] = *(const bf16x8*)(lds + (unsigned)(BB) * 65536u + 32768u       \
                            + (KK) * 16384u + (unsigned)rb * 64u + pb * 16u);        \
        } } while (0)

#define MFMA8(MIH) do {                                                              \
      _Pragma("unroll")                                                              \
      for (int mi2 = 0; mi2 < 2; ++mi2)                                              \
        _Pragma("unroll")                                                            \
        for (int nj = 0; nj < 2; ++nj)                                               \
          _Pragma("unroll")                                                          \
          for (int ks = 0; ks < 2; ++ks)                                             \
            acc[((MIH) * 2 + mi2) * 2 + nj] = __builtin_amdgcn_mfma_f32_32x32x16_bf16( \
                af[mi2][ks], bg[nj][ks], acc[((MIH) * 2 + mi2) * 2 + nj], 0, 0, 0);  \
    } while (0)

// One K-tile = 4 phases; single vmcnt(6) at end of ph4 covers tile u+1's reads.
#define KTILE(U, BB) do {                                                            \
      const int tt1 = ((U) + 1 < NTILE) ? (U) + 1 : (U) - 1;                         \
      const int tt2 = ((U) + 2 < NTILE) ? (U) + 2 : (U);                             \
      /* phase 1: kk=0 m-half 0 */                                                   \
      LOAD_B32(0, BB); LOAD_A32(0, 0, BB);                                           \
      STAGE_A(1, tt1, 1 - (BB));                                                     \
      BAR(); WAITLGKM(); SCHEDB();                                                   \
      __builtin_amdgcn_s_setprio(1); MFMA8(0); __builtin_amdgcn_s_setprio(0);        \
      BAR(); SCHEDB();                                                               \
      /* phase 2: kk=0 m-half 1 */                                                   \
      LOAD_A32(1, 0, BB);                                                            \
      STAGE_B(0, tt2, BB);                                                           \
      BAR(); WAITLGKM(); SCHEDB();                                                   \
      __builtin_amdgcn_s_setprio(1); MFMA8(1); __builtin_amdgcn_s_setprio(0);        \
      BAR(); SCHEDB();                                                               \
      /* phase 3: kk=1 m-half 0 */                                                   \
      LOAD_B32(1, BB); LOAD_A32(0, 1, BB);                                           \
      STAGE_A(0, tt2, BB);                                                           \
      BAR(); WAITLGKM(); SCHEDB();                                                   \
      __builtin_amdgcn_s_setprio(1); MFMA8(0); __builtin_amdgcn_s_setprio(0);        \
      BAR(); SCHEDB();                                                               \
      /* phase 4: kk=1 m-half 1 */                                                   \
      LOAD_A32(1, 1, BB);                                                            \
      STAGE_B(1, tt2, BB);                                                           \
      BAR(); WAITLGKM(); SCHEDB();                                                   \
      __builtin_amdgcn_s_setprio(1); MFMA8(1); __builtin_amdgcn_s_setprio(0);        \
      WAITVM6(); BAR(); SCHEDB();                                                    \
    } while (0)

    f32x16 acc[8];
    #pragma unroll
    for (int i = 0; i < 8; ++i) acc[i] = (f32x16)0.0f;
    bf16x8 af[2][2], bg[2][2];

    // Prologue: tile0 {Ak0,Bk0,Ak1,Bk1}, tile1 {Ak0,Bk0,Bk1}; 14 issued, need 8 -> vmcnt(6).
    STAGE_A(0, 0, 0); STAGE_B(0, 0, 0); STAGE_A(1, 0, 0); STAGE_B(1, 0, 0);
    STAGE_A(0, 1, 1); STAGE_B(0, 1, 1); STAGE_B(1, 1, 1);
    WAITVM6();
    BAR(); SCHEDB();

    #pragma unroll 1
    for (int u = 0; u < NTILE; u += 2) {
        KTILE(u, 0);
        KTILE(u + 1, 1);
    }
    WAITVM0();   // drain idempotent tail reloads before LDS dealloc

    // Epilogue: 32x32 C/D layout col=lane&31, row=(reg&3)+8*(reg>>2)+4*(lane>>5)
    #pragma unroll
    for (int mi = 0; mi < 4; ++mi)
        #pragma unroll
        for (int nj = 0; nj < 2; ++nj) {
            int n = n0 + wc * 64 + nj * 32 + l31;
            float bv = bias[n];
            int mbase = m0 + wr * 128 + mi * 32 + 4 * h32;
            #pragma unroll
            for (int reg = 0; reg < 16; ++reg) {
                int row = mbase + (reg & 3) + 8 * (reg >> 2);
                C[(size_t)row * N_TOT + n] = acc[mi * 2 + nj][reg] + bv;
            }
        }
}

extern "C" void kernel_launch(void* const* d_in, const int* in_sizes, int n_in,
                              void* d_out, int out_size, void* d_ws, size_t ws_size,
                              hipStream_t stream) {
    const float* x    = (const float*)d_in[0];
    const float* w    = (const float*)d_in[1];
    const float* bias = (const float*)d_in[2];
    float* out = (float*)d_out;

    unsigned short* wb = (unsigned short*)d_ws;                      // 32 MiB
    unsigned short* xb = wb + (size_t)N_TOT * K_TOT;                 // +64 MiB

    quant_w_kernel<<<(N_TOT * K_TOT / 128) / 4, 256, 0, stream>>>(w, wb);
    cvt_x_kernel<<<2048, 256, 0, stream>>>(x, xb);

    hipFuncSetAttribute(reinterpret_cast<const void*>(gemm_kernel),
                        hipFuncAttributeMaxDynamicSharedMemorySize, 131072);
    gemm_kernel<<<512, 512, 131072, stream>>>(xb, wb, bias, out);
}

// Round 6
// 287.498 us; speedup vs baseline: 1.1406x; 1.1406x over previous
//
#include <hip/hip_runtime.h>
#include <stdint.h>

#define M_TOT 8192
#define N_TOT 4096
#define K_TOT 4096
#define NTILE 64   // K-tiles of BK=64

typedef __attribute__((ext_vector_type(8))) short bf16x8;
typedef __attribute__((ext_vector_type(4))) float f32x4;
typedef __attribute__((ext_vector_type(2))) unsigned short u16x2;
typedef __attribute__((ext_vector_type(4))) unsigned short u16x4;

typedef const __attribute__((address_space(1))) void* gas1;
typedef __attribute__((address_space(3))) void* las3;

__device__ __forceinline__ unsigned short bf16_rne(float f) {
    union { float f; unsigned int u; } v; v.f = f;
    unsigned int u = v.u;
    return (unsigned short)((u + 0x7FFFu + ((u >> 16) & 1u)) >> 16);
}

// Exact collapse of the reference FP4(E2M1) quant-dequant on a = |w|/scale.
__device__ __forceinline__ float fp4_qdq(float wv, float scale) {
    float a = fabsf(wv) / scale;
    float q;
    if      (a <= 0.25f) q = 0.0f;
    else if (a <  1.0f ) q = 0.5f;
    else if (a <= 1.25f) q = 1.0f;
    else if (a <  2.0f ) q = 1.5f;
    else if (a <= 2.5f ) q = 2.0f;
    else if (a <  4.0f ) q = 3.0f;
    else if (a <= 5.0f ) q = 4.0f;
    else                 q = 6.0f;
    float d = q * scale;
    return wv < 0.0f ? -d : d;
}

// Fused prep: blocks [0,2048) convert x f32->bf16; blocks [2048,4096) quantize w.
__global__ __launch_bounds__(256) void prep_kernel(const float* __restrict__ w,
                                                   unsigned short* __restrict__ wb,
                                                   const float* __restrict__ x,
                                                   unsigned short* __restrict__ xb) {
    if (blockIdx.x < 2048) {
        const int total4 = (M_TOT * K_TOT) / 4;
        int stride = 2048 * 256;
        for (int i = blockIdx.x * 256 + threadIdx.x; i < total4; i += stride) {
            float4 v = ((const float4*)x)[i];
            u16x4 o;
            o.x = bf16_rne(v.x); o.y = bf16_rne(v.y);
            o.z = bf16_rne(v.z); o.w = bf16_rne(v.w);
            ((u16x4*)xb)[i] = o;
        }
    } else {
        int wv0 = (blockIdx.x - 2048) * 4 + (threadIdx.x >> 6);
        int lane = threadIdx.x & 63;
        const int ngroups = (N_TOT * K_TOT) / 128;   // 131072
        for (int g = wv0; g < ngroups; g += 2048 * 4) {
            size_t base = (size_t)g * 128;
            float2 v = ((const float2*)(w + base))[lane];
            float mx = fmaxf(fabsf(v.x), fabsf(v.y));
            #pragma unroll
            for (int off = 32; off; off >>= 1) mx = fmaxf(mx, __shfl_xor(mx, off));
            float scale = fmaxf(mx / 6.0f, 1e-8f);
            u16x2 o;
            o.x = bf16_rne(fp4_qdq(v.x, scale));
            o.y = bf16_rne(fp4_qdq(v.y, scale));
            *(u16x2*)(wb + base + (size_t)lane * 2) = o;
        }
    }
}

// -------- 256x256 8-phase GEMM (R3 skeleton, compiler-scheduled lgkm) --------
// C[m][n] = sum_k A[m][k]*B[n][k] + bias[n]; A,B bf16 K-contig, C f32.
// 512 threads = 8 waves (2M x 4N). BK=64 split into k-halves of 32.
// LDS: 2 buffers x { A_k0, A_k1, B_k0, B_k1 } of [256 rows][32 cols] bf16.
// Rotation swizzle within 64B rows: LDS pos p holds source granule (p-(r>>1))&3.
// Two barriers per phase (proven R3 structure); single counted vmcnt(6) per
// K-tile. NO explicit lgkmcnt(0): the compiler emits fine-grained lgkmcnt(N)
// before each MFMA, letting trailing ds_reads hide under the MFMA stream.

#define BAR()      __builtin_amdgcn_s_barrier()
#define SCHEDB()   __builtin_amdgcn_sched_barrier(0)
#define WAITVM6()  asm volatile("s_waitcnt vmcnt(6)" ::: "memory")
#define WAITVM0()  asm volatile("s_waitcnt vmcnt(0)" ::: "memory")

__global__ __launch_bounds__(512) void gemm_kernel(const unsigned short* __restrict__ A,
                                                   const unsigned short* __restrict__ B,
                                                   const float* __restrict__ bias,
                                                   float* __restrict__ C) {
    extern __shared__ unsigned char lds[];   // 131072 bytes

    // 2D-chunked XCD swizzle: XCD = bid&7 owns a 16tm x 4tn rectangle;
    // its 32 concurrently-resident blocks cover 8tm x 4tn -> L2 set ~384KB.
    const int bid = blockIdx.x;
    const int xcd = bid & 7;
    const int idx = bid >> 3;          // 0..63
    const int tm = ((xcd >> 2) << 4) + (idx >> 2);   // 0..31
    const int tn = ((xcd & 3) << 2) + (idx & 3);     // 0..15
    const int m0 = tm << 8, n0 = tn << 8;

    const int t = threadIdx.x;
    const int l = t & 63;
    const int wid = t >> 6;
    const int wr = wid >> 2;   // 0..1
    const int wc = wid & 3;    // 0..3
    const int l15 = l & 15;
    const int q4 = l >> 4;

    // Staging: thread t covers granules G0=t, G1=512+t of each 1024-granule region.
    // Row r=G>>2, LDS pos p=G&3 holds source granule s=(p-(r>>1))&3.
    const int r0g = t >> 2,        p0g = t & 3;
    const int r1g = (512 + t) >> 2, p1g = t & 3;
    const int s0g = (p0g - (r0g >> 1)) & 3;
    const int s1g = (p1g - (r1g >> 1)) & 3;
    const unsigned short* arow0 = A + (size_t)(m0 + r0g) * K_TOT + s0g * 8;
    const unsigned short* arow1 = A + (size_t)(m0 + r1g) * K_TOT + s1g * 8;
    const unsigned short* brow0 = B + (size_t)(n0 + r0g) * K_TOT + s0g * 8;
    const unsigned short* brow1 = B + (size_t)(n0 + r1g) * K_TOT + s1g * 8;
    const unsigned lo0 = (unsigned)t * 16u;
    const unsigned lo1 = lo0 + 8192u;

#define STAGE(ROW0, ROW1, MATOFF, KK, TT, BB) do {                                   \
      const unsigned _base = (unsigned)(BB) * 65536u + (MATOFF) + (KK) * 16384u;     \
      const int _ko = (TT) * 64 + (KK) * 32;                                         \
      __builtin_amdgcn_global_load_lds((gas1)(ROW0 + _ko), (las3)(lds + _base + lo0), 16, 0, 0); \
      __builtin_amdgcn_global_load_lds((gas1)(ROW1 + _ko), (las3)(lds + _base + lo1), 16, 0, 0); \
    } while (0)
#define STAGE_A(KK, TT, BB) STAGE(arow0, arow1, 0u, KK, TT, BB)
#define STAGE_B(KK, TT, BB) STAGE(brow0, brow1, 32768u, KK, TT, BB)

#define LOAD_A(QM, KK, BB) do {                                                      \
      _Pragma("unroll")                                                              \
      for (int i = 0; i < 4; ++i) {                                                  \
        int ra = wr * 128 + (QM) * 64 + i * 16 + l15;                                \
        unsigned pa = (unsigned)((q4 + (ra >> 1)) & 3);                              \
        af[i] = *(const bf16x8*)(lds + (unsigned)(BB) * 65536u + (KK) * 16384u       \
                                 + (unsigned)ra * 64u + pa * 16u);                   \
      } } while (0)

#define LOAD_B(KK, BB) do {                                                          \
      _Pragma("unroll")                                                              \
      for (int n = 0; n < 4; ++n) {                                                  \
        int rb = wc * 64 + n * 16 + l15;                                             \
        unsigned pb = (unsigned)((q4 + (rb >> 1)) & 3);                              \
        bg[n] = *(const bf16x8*)(lds + (unsigned)(BB) * 65536u + 32768u              \
                                 + (KK) * 16384u + (unsigned)rb * 64u + pb * 16u);   \
      } } while (0)

#define MFMA16(QM) do {                                                              \
      _Pragma("unroll")                                                              \
      for (int i = 0; i < 4; ++i)                                                    \
        _Pragma("unroll")                                                            \
        for (int n = 0; n < 4; ++n)                                                  \
          acc[(QM) * 4 + i][n] = __builtin_amdgcn_mfma_f32_16x16x32_bf16(            \
              af[i], bg[n], acc[(QM) * 4 + i][n], 0, 0, 0);                          \
    } while (0)

// One K-tile = 4 phases (R3 structure).
// ph1 reads Ak0,Bk0; stages Ak1(u+1)->buf^1. ph2 reads Ak0; stages Bk0(u+2).
// ph3 reads Ak1,Bk1; stages Ak0(u+2). ph4 reads Ak1; stages Bk1(u+2); vmcnt(6).
// vmcnt(6) at end of ph4 forces the 4 oldest regions (= all of tile u+1) done.
#define KTILE(U, BB) do {                                                            \
      const int tt1 = ((U) + 1 < NTILE) ? (U) + 1 : (U) - 1;                         \
      const int tt2 = ((U) + 2 < NTILE) ? (U) + 2 : (U);                             \
      /* phase 1: kk=0 qm=0 */                                                       \
      LOAD_B(0, BB); LOAD_A(0, 0, BB);                                               \
      STAGE_A(1, tt1, 1 - (BB));                                                     \
      BAR();                                                                         \
      __builtin_amdgcn_s_setprio(1); MFMA16(0); __builtin_amdgcn_s_setprio(0);       \
      BAR();                                                                         \
      /* phase 2: kk=0 qm=1 */                                                       \
      LOAD_A(1, 0, BB);                                                              \
      STAGE_B(0, tt2, BB);                                                           \
      BAR();                                                                         \
      __builtin_amdgcn_s_setprio(1); MFMA16(1); __builtin_amdgcn_s_setprio(0);       \
      BAR();                                                                         \
      /* phase 3: kk=1 qm=0 */                                                       \
      LOAD_B(1, BB); LOAD_A(0, 1, BB);                                               \
      STAGE_A(0, tt2, BB);                                                           \
      BAR();                                                                         \
      __builtin_amdgcn_s_setprio(1); MFMA16(0); __builtin_amdgcn_s_setprio(0);       \
      BAR();                                                                         \
      /* phase 4: kk=1 qm=1 */                                                       \
      LOAD_A(1, 1, BB);                                                              \
      STAGE_B(1, tt2, BB);                                                           \
      BAR();                                                                         \
      __builtin_amdgcn_s_setprio(1); MFMA16(1); __builtin_amdgcn_s_setprio(0);       \
      WAITVM6(); SCHEDB(); BAR();                                                    \
    } while (0)

    f32x4 acc[8][4];
    #pragma unroll
    for (int i = 0; i < 8; ++i)
        #pragma unroll
        for (int j = 0; j < 4; ++j)
            acc[i][j] = (f32x4)0.0f;
    bf16x8 af[4], bg[4];

    // Prologue: tile0 {Ak0,Bk0,Ak1,Bk1}, tile1 {Ak0,Bk0,Bk1}; 14 issued,
    // need first 8 (all of tile 0) -> vmcnt(6).
    STAGE_A(0, 0, 0); STAGE_B(0, 0, 0); STAGE_A(1, 0, 0); STAGE_B(1, 0, 0);
    STAGE_A(0, 1, 1); STAGE_B(0, 1, 1); STAGE_B(1, 1, 1);
    WAITVM6(); SCHEDB();
    BAR();

    #pragma unroll 1
    for (int u = 0; u < NTILE; u += 2) {
        KTILE(u, 0);
        KTILE(u + 1, 1);
    }
    WAITVM0();   // drain idempotent tail reloads before LDS dealloc

    // Epilogue: C/D layout col=lane&15, row=(lane>>4)*4+reg
    #pragma unroll
    for (int j = 0; j < 4; ++j) {
        int n = n0 + wc * 64 + j * 16 + l15;
        float bv = bias[n];
        #pragma unroll
        for (int i = 0; i < 8; ++i) {
            int mb = m0 + wr * 128 + i * 16 + (q4 << 2);
            #pragma unroll
            for (int r = 0; r < 4; ++r)
                C[(size_t)(mb + r) * N_TOT + n] = acc[i][j][r] + bv;
        }
    }
}

extern "C" void kernel_launch(void* const* d_in, const int* in_sizes, int n_in,
                              void* d_out, int out_size, void* d_ws, size_t ws_size,
                              hipStream_t stream) {
    const float* x    = (const float*)d_in[0];
    const float* w    = (const float*)d_in[1];
    const float* bias = (const float*)d_in[2];
    float* out = (float*)d_out;

    unsigned short* wb = (unsigned short*)d_ws;                      // 32 MiB
    unsigned short* xb = wb + (size_t)N_TOT * K_TOT;                 // +64 MiB

    prep_kernel<<<4096, 256, 0, stream>>>(w, wb, x, xb);

    hipFuncSetAttribute(reinterpret_cast<const void*>(gemm_kernel),
                        hipFuncAttributeMaxDynamicSharedMemorySize, 131072);
    gemm_kernel<<<512, 512, 131072, stream>>>(xb, wb, bias, out);
}